// Round 1
// baseline (1774.094 us; speedup 1.0000x reference)
//
#include <hip/hip_runtime.h>
#include <hip/hip_bf16.h>
#include <math.h>

#define NN    8192
#define TT    64
#define DIN   64
#define RR    256
#define DOUT  64
#define HID   128
#define CATD  1024
#define NE    131072
#define MASKW 256              // 8192 bits / 32
#define HS_PAD (RR + 8)
#define XS_PAD (DIN + 8)
#define BN    16

// ---------------- setup kernels ----------------

__global__ __launch_bounds__(256) void zero_mask_kernel(uint4* mask4, int n4) {
  int i = blockIdx.x * 256 + threadIdx.x;
  if (i < n4) mask4[i] = make_uint4(0u, 0u, 0u, 0u);
}

// dst[c][r] = src[r][c]; src is [rows][cols]
__global__ __launch_bounds__(256) void transpose_kernel(const float* __restrict__ src,
                                                        float* __restrict__ dst,
                                                        int rows, int cols) {
  int idx = blockIdx.x * 256 + threadIdx.x;
  if (idx < rows * cols) {
    int r = idx / cols, c = idx - r * cols;
    dst[c * rows + r] = src[idx];
  }
}

__global__ __launch_bounds__(256) void edge_kernel(const int* __restrict__ eidx,
                                                   unsigned int* __restrict__ mask) {
  int e = blockIdx.x * 256 + threadIdx.x;
  if (e < NE) {
    int u = eidx[e];
    int v = eidx[NE + e];
    atomicOr(&mask[(size_t)u * MASKW + (v >> 5)], 1u << (v & 31));
    atomicOr(&mask[(size_t)v * MASKW + (u >> 5)], 1u << (u & 31));
  }
}

__global__ __launch_bounds__(64) void degree_kernel(const unsigned int* __restrict__ mask,
                                                    float* __restrict__ dinv) {
  int n = blockIdx.x;
  int lane = threadIdx.x;
  uint4 mw = *(const uint4*)(mask + (size_t)n * MASKW + lane * 4);
  int c = __popc(mw.x) + __popc(mw.y) + __popc(mw.z) + __popc(mw.w);
#pragma unroll
  for (int off = 32; off > 0; off >>= 1) c += __shfl_down(c, off, 64);
  if (lane == 0) {
    dinv[n] = (c > 0) ? fminf(1.0f / sqrtf((float)c), 1e6f) : 0.0f;
  }
}

// ---------------- ESN ----------------
// block: 256 threads (4 waves), BN=16 nodes. Thread tile: 4 nodes x 4 r.
// wave -> (r-half, n-half); lane -> (rg = lane&31 -> 4 r's, ng = lane>>5 -> 4 n's)
__global__ __launch_bounds__(256) void esn_kernel(
    const float* __restrict__ x,      // [N][T][DIN]
    const float* __restrict__ WinT,   // [DIN][R]
    const float* __restrict__ WresT,  // [R][R]
    float* __restrict__ cat)          // [N][CATD], writes cols 0..255
{
  __shared__ float hs[BN][HS_PAD];    // n-major h, padded
  __shared__ float xs[BN][XS_PAD];
  const int tid  = threadIdx.x;
  const int lane = tid & 63;
  const int wave = tid >> 6;
  const int r0 = (wave & 1) * 128 + (lane & 31) * 4;
  const int n0 = (wave >> 1) * 8 + (lane >> 5) * 4;
  const long gn0 = (long)blockIdx.x * BN;

  float hreg[4][4];
#pragma unroll
  for (int a = 0; a < 4; ++a)
#pragma unroll
    for (int b = 0; b < 4; ++b) hreg[a][b] = 0.0f;
  for (int i = tid; i < BN * HS_PAD; i += 256) ((float*)hs)[i] = 0.0f;

  for (int t = 0; t < TT; ++t) {
    // stage x_t tile: x[n][t][d], coalesced 64-float rows
    for (int i = tid; i < BN * DIN; i += 256) {
      int n = i >> 6, d = i & 63;
      xs[n][d] = x[(gn0 + n) * (long)(TT * DIN) + t * DIN + d];
    }
    __syncthreads();

    float acc[4][4];
#pragma unroll
    for (int a = 0; a < 4; ++a)
#pragma unroll
      for (int b = 0; b < 4; ++b) acc[a][b] = 0.0f;

#pragma unroll 4
    for (int d = 0; d < DIN; ++d) {
      float4 w = *(const float4*)(WinT + d * RR + r0);
#pragma unroll
      for (int a = 0; a < 4; ++a) {
        float av = xs[n0 + a][d];
        acc[a][0] += av * w.x; acc[a][1] += av * w.y;
        acc[a][2] += av * w.z; acc[a][3] += av * w.w;
      }
    }
#pragma unroll 4
    for (int j = 0; j < RR; ++j) {
      float4 w = *(const float4*)(WresT + j * RR + r0);
#pragma unroll
      for (int a = 0; a < 4; ++a) {
        float av = hs[n0 + a][j];
        acc[a][0] += av * w.x; acc[a][1] += av * w.y;
        acc[a][2] += av * w.z; acc[a][3] += av * w.w;
      }
    }
    __syncthreads();   // all reads of hs(t) done before overwrite

#pragma unroll
    for (int a = 0; a < 4; ++a)
#pragma unroll
      for (int b = 0; b < 4; ++b) {
        float hn = 0.7f * hreg[a][b] + 0.3f * tanhf(acc[a][b]);
        hreg[a][b] = hn;
        hs[n0 + a][r0 + b] = hn;
      }
    // loop-top __syncthreads (after x staging) separates these writes
    // from next step's reads.
  }

#pragma unroll
  for (int a = 0; a < 4; ++a) {
    float4 v = make_float4(hreg[a][0], hreg[a][1], hreg[a][2], hreg[a][3]);
    *(float4*)(cat + (gn0 + n0 + a) * CATD + r0) = v;
  }
}

// ---------------- SpMV hop (bitmask, dedup'd) ----------------
// out[n][r] = dinv[n] * sum_{j in adj(n)} dinv[j] * in[j][r]
__global__ __launch_bounds__(256) void spmv_kernel(
    const unsigned int* __restrict__ mask, const float* __restrict__ dinv,
    float* __restrict__ catbuf, int k)
{
  __shared__ unsigned int mrow[MASKW];
  const int n = blockIdx.x;
  const int tid = threadIdx.x;
  mrow[tid] = mask[(size_t)n * MASKW + tid];
  __syncthreads();
  const float* in = catbuf + (size_t)(k - 1) * RR;  // slice k-1, row stride CATD
  float acc = 0.0f;
  for (int w = 0; w < MASKW; ++w) {
    unsigned int m = mrow[w];
    while (m) {
      int b = __ffs(m) - 1;
      m &= m - 1;
      int j = __builtin_amdgcn_readfirstlane(w * 32 + b);  // uniform -> s_load dinv
      acc += dinv[j] * in[(size_t)j * CATD + tid];
    }
  }
  catbuf[(size_t)n * CATD + (size_t)k * RR + tid] = acc * dinv[n];
}

// ---------------- fused readout: GEMM1+GELU+GEMM2+LayerNorm ----------------
__global__ __launch_bounds__(256) void readout_kernel(
    const float* __restrict__ cat, const float* __restrict__ W1T,
    const float* __restrict__ b1, const float* __restrict__ W2T,
    const float* __restrict__ b2, const float* __restrict__ gamma,
    const float* __restrict__ beta, float* __restrict__ out)
{
  __shared__ float catl[8][CATD];
  __shared__ float z1[8][HID];
  __shared__ float z2[8][DOUT];
  const int tid = threadIdx.x;
  const long gn0 = (long)blockIdx.x * 8;

  const float4* src = (const float4*)(cat + gn0 * CATD);
  float4* dstl = (float4*)catl;
  for (int i = tid; i < 8 * CATD / 4; i += 256) dstl[i] = src[i];
  __syncthreads();

  {
    const int i = tid & 127;
    const int nh = tid >> 7;       // 2 halves x 4 nodes
    float a0 = b1[i], a1 = a0, a2 = a0, a3 = a0;
#pragma unroll 4
    for (int c = 0; c < CATD; ++c) {
      float w = W1T[c * HID + i];
      a0 += w * catl[nh * 4 + 0][c];
      a1 += w * catl[nh * 4 + 1][c];
      a2 += w * catl[nh * 4 + 2][c];
      a3 += w * catl[nh * 4 + 3][c];
    }
    const float is2 = 0.70710678118654752f;
    z1[nh * 4 + 0][i] = 0.5f * a0 * (1.0f + erff(a0 * is2));
    z1[nh * 4 + 1][i] = 0.5f * a1 * (1.0f + erff(a1 * is2));
    z1[nh * 4 + 2][i] = 0.5f * a2 * (1.0f + erff(a2 * is2));
    z1[nh * 4 + 3][i] = 0.5f * a3 * (1.0f + erff(a3 * is2));
  }
  __syncthreads();
  {
    const int o = tid & 63;
    const int q = tid >> 6;        // 4 quarters x 2 nodes
    float a0 = b2[o], a1 = b2[o];
#pragma unroll 4
    for (int i2 = 0; i2 < HID; ++i2) {
      float w = W2T[i2 * DOUT + o];
      a0 += w * z1[q * 2 + 0][i2];
      a1 += w * z1[q * 2 + 1][i2];
    }
    z2[q * 2 + 0][o] = a0;
    z2[q * 2 + 1][o] = a1;
  }
  __syncthreads();
  {
    const int o = tid & 63;
    const int q = tid >> 6;
#pragma unroll
    for (int m = 0; m < 2; ++m) {
      const int n = q * 2 + m;
      float s = 0.0f, s2 = 0.0f;
#pragma unroll 8
      for (int k2 = 0; k2 < DOUT; ++k2) { float v = z2[n][k2]; s += v; s2 += v * v; }
      float mu  = s * (1.0f / 64.0f);
      float var = s2 * (1.0f / 64.0f) - mu * mu;
      float v = (z2[n][o] - mu) * rsqrtf(var + 1e-5f);
      out[(gn0 + n) * DOUT + o] = v * gamma[o] + beta[o];
    }
  }
}

// ---------------- launch ----------------

extern "C" void kernel_launch(void* const* d_in, const int* in_sizes, int n_in,
                              void* d_out, int out_size, void* d_ws, size_t ws_size,
                              hipStream_t stream) {
  const float* x     = (const float*)d_in[0];
  const int*   eidx  = (const int*)d_in[1];
  const float* W_in  = (const float*)d_in[2];
  const float* W_res = (const float*)d_in[3];
  const float* W1    = (const float*)d_in[4];
  const float* b1    = (const float*)d_in[5];
  const float* W2    = (const float*)d_in[6];
  const float* b2    = (const float*)d_in[7];
  const float* gamma = (const float*)d_in[8];
  const float* beta  = (const float*)d_in[9];
  float* out = (float*)d_out;

  char* ws = (char*)d_ws;
  size_t off = 0;
  unsigned int* mask = (unsigned int*)(ws + off); off += (size_t)NN * MASKW * 4;      // 8 MB
  float* cat   = (float*)(ws + off); off += (size_t)NN * CATD * 4;                    // 32 MB
  float* dinv  = (float*)(ws + off); off += (size_t)NN * 4;
  float* WinT  = (float*)(ws + off); off += (size_t)DIN * RR * 4;
  float* WresT = (float*)(ws + off); off += (size_t)RR * RR * 4;
  float* W1T   = (float*)(ws + off); off += (size_t)CATD * HID * 4;
  float* W2T   = (float*)(ws + off); off += (size_t)HID * DOUT * 4;

  // adjacency bitmask (dedup identical to reference's idempotent .set)
  zero_mask_kernel<<<2048, 256, 0, stream>>>((uint4*)mask, NN * MASKW / 4);
  transpose_kernel<<<64, 256, 0, stream>>>(W_in, WinT, RR, DIN);
  transpose_kernel<<<256, 256, 0, stream>>>(W_res, WresT, RR, RR);
  transpose_kernel<<<512, 256, 0, stream>>>(W1, W1T, HID, CATD);
  transpose_kernel<<<32, 256, 0, stream>>>(W2, W2T, DOUT, HID);
  edge_kernel<<<(NE + 255) / 256, 256, 0, stream>>>(eidx, mask);
  degree_kernel<<<NN, 64, 0, stream>>>(mask, dinv);

  esn_kernel<<<NN / BN, 256, 0, stream>>>(x, WinT, WresT, cat);

  for (int k = 1; k <= 3; ++k)
    spmv_kernel<<<NN, 256, 0, stream>>>(mask, dinv, cat, k);

  readout_kernel<<<NN / 8, 256, 0, stream>>>(cat, W1T, b1, W2T, b2, gamma, beta, out);
}

// Round 2
// 622.157 us; speedup vs baseline: 2.8515x; 2.8515x over previous
//
#include <hip/hip_runtime.h>
#include <hip/hip_bf16.h>
#include <math.h>

#define NN    8192
#define TT    64
#define DIN   64
#define RR    256
#define DOUT  64
#define HID   128
#define CATD  1024
#define NE    131072
#define MASKW 256              // 8192 bits / 32
#define HROW  264              // 256 + 8 bf16 pad (132 dwords = 4 mod 32 banks)

typedef __attribute__((ext_vector_type(8))) short s16x8;   // 8 bf16 in 4 VGPRs
typedef __attribute__((ext_vector_type(4))) float f32x4;

static __device__ __forceinline__ unsigned short f2bs(float f) {
  union { __hip_bfloat16 b; unsigned short u; } cv;
  cv.b = __float2bfloat16(f);
  return cv.u;
}

static __device__ __forceinline__ float fast_tanh(float v) {
  // tanh(x) = 1 - 2/(exp2(x*2*log2e)+1); exact saturation at +-inf
  float e = __builtin_amdgcn_exp2f(v * 2.8853900817779268f);
  return 1.0f - 2.0f * __builtin_amdgcn_rcpf(e + 1.0f);
}

// ---------------- setup kernels ----------------

__global__ __launch_bounds__(256) void zero_mask_kernel(uint4* mask4, int n4) {
  int i = blockIdx.x * 256 + threadIdx.x;
  if (i < n4) mask4[i] = make_uint4(0u, 0u, 0u, 0u);
}

// dst[c][r] = src[r][c]; src is [rows][cols]
__global__ __launch_bounds__(256) void transpose_kernel(const float* __restrict__ src,
                                                        float* __restrict__ dst,
                                                        int rows, int cols) {
  int idx = blockIdx.x * 256 + threadIdx.x;
  if (idx < rows * cols) {
    int r = idx / cols, c = idx - r * cols;
    dst[c * rows + r] = src[idx];
  }
}

__global__ __launch_bounds__(256) void edge_kernel(const int* __restrict__ eidx,
                                                   unsigned int* __restrict__ mask) {
  int e = blockIdx.x * 256 + threadIdx.x;
  if (e < NE) {
    int u = eidx[e];
    int v = eidx[NE + e];
    atomicOr(&mask[(size_t)u * MASKW + (v >> 5)], 1u << (v & 31));
    atomicOr(&mask[(size_t)v * MASKW + (u >> 5)], 1u << (u & 31));
  }
}

__global__ __launch_bounds__(64) void degree_kernel(const unsigned int* __restrict__ mask,
                                                    float* __restrict__ dinv) {
  int n = blockIdx.x;
  int lane = threadIdx.x;
  uint4 mw = *(const uint4*)(mask + (size_t)n * MASKW + lane * 4);
  int c = __popc(mw.x) + __popc(mw.y) + __popc(mw.z) + __popc(mw.w);
#pragma unroll
  for (int off = 32; off > 0; off >>= 1) c += __shfl_down(c, off, 64);
  if (lane == 0) {
    dinv[n] = (c > 0) ? fminf(1.0f / sqrtf((float)c), 1e6f) : 0.0f;
  }
}

// ---------------- ESN via bf16 MFMA ----------------
// Block: 256 threads = 4 waves, 16 nodes. Wave w owns output cols [w*64, w*64+64).
// MFMA 16x16x32: A = h tile [16 nodes x 32 j], B = W_res rows [32 j x 16 r].
// B-frag (lane&15 = col, (lane>>4)*8+j = k) loads DIRECTLY from row-major W.
// State h kept fp32 in C-frags; bf16 only at MFMA inputs.
__global__ __launch_bounds__(256) void esn_mfma_kernel(
    const float* __restrict__ x,      // [N][T][DIN]
    const float* __restrict__ W_in,   // [R][DIN] row-major
    const float* __restrict__ W_res,  // [R][R]   row-major
    float* __restrict__ cat)          // [N][CATD], writes cols 0..255
{
  __shared__ unsigned short hs[2][16][HROW];   // bf16 bits, ping-pong
  const int tid  = threadIdx.x;
  const int lane = tid & 63;
  const int w    = tid >> 6;        // wave 0..3
  const int lr   = lane & 15;       // within-tile row (A) / col (B)
  const int lg   = lane >> 4;       // k-group 0..3
  const long gn0 = (long)blockIdx.x * 16;

  // ---- preload W fragments (kept in VGPRs across all 64 steps) ----
  s16x8 wres[4][8];                 // [n-tile][k-tile]
  s16x8 win[4][2];
#pragma unroll
  for (int nt = 0; nt < 4; ++nt) {
    const int r = w * 64 + nt * 16 + lr;
#pragma unroll
    for (int kt = 0; kt < 8; ++kt) {
      const float4 f0 = *(const float4*)(W_res + r * RR + kt * 32 + lg * 8);
      const float4 f1 = *(const float4*)(W_res + r * RR + kt * 32 + lg * 8 + 4);
      s16x8 v;
      v[0] = (short)f2bs(f0.x); v[1] = (short)f2bs(f0.y);
      v[2] = (short)f2bs(f0.z); v[3] = (short)f2bs(f0.w);
      v[4] = (short)f2bs(f1.x); v[5] = (short)f2bs(f1.y);
      v[6] = (short)f2bs(f1.z); v[7] = (short)f2bs(f1.w);
      wres[nt][kt] = v;
    }
#pragma unroll
    for (int kt = 0; kt < 2; ++kt) {
      const float4 f0 = *(const float4*)(W_in + r * DIN + kt * 32 + lg * 8);
      const float4 f1 = *(const float4*)(W_in + r * DIN + kt * 32 + lg * 8 + 4);
      s16x8 v;
      v[0] = (short)f2bs(f0.x); v[1] = (short)f2bs(f0.y);
      v[2] = (short)f2bs(f0.z); v[3] = (short)f2bs(f0.w);
      v[4] = (short)f2bs(f1.x); v[5] = (short)f2bs(f1.y);
      v[6] = (short)f2bs(f1.z); v[7] = (short)f2bs(f1.w);
      win[nt][kt] = v;
    }
  }

  // zero h buffer 0
  for (int i = tid; i < 16 * HROW; i += 256) ((unsigned short*)hs[0])[i] = 0;

  f32x4 hreg[4];
#pragma unroll
  for (int nt = 0; nt < 4; ++nt) hreg[nt] = (f32x4){0.f, 0.f, 0.f, 0.f};

  __syncthreads();

  const float* xrow = x + (gn0 + lr) * (long)(TT * DIN);

  for (int t = 0; t < TT; ++t) {
    const int p = t & 1;

    // x A-frags for this step (same for all 4 waves -> L1 broadcast)
    s16x8 xa[2];
#pragma unroll
    for (int kt = 0; kt < 2; ++kt) {
      const float4 f0 = *(const float4*)(xrow + t * DIN + kt * 32 + lg * 8);
      const float4 f1 = *(const float4*)(xrow + t * DIN + kt * 32 + lg * 8 + 4);
      s16x8 v;
      v[0] = (short)f2bs(f0.x); v[1] = (short)f2bs(f0.y);
      v[2] = (short)f2bs(f0.z); v[3] = (short)f2bs(f0.w);
      v[4] = (short)f2bs(f1.x); v[5] = (short)f2bs(f1.y);
      v[6] = (short)f2bs(f1.z); v[7] = (short)f2bs(f1.w);
      xa[kt] = v;
    }

    f32x4 acc[4];
#pragma unroll
    for (int nt = 0; nt < 4; ++nt) acc[nt] = (f32x4){0.f, 0.f, 0.f, 0.f};

    // h @ W_res^T : load one A-frag at a time (keeps VGPRs low)
#pragma unroll
    for (int kt = 0; kt < 8; ++kt) {
      s16x8 ha = *(const s16x8*)(&hs[p][lr][kt * 32 + lg * 8]);
#pragma unroll
      for (int nt = 0; nt < 4; ++nt)
        acc[nt] = __builtin_amdgcn_mfma_f32_16x16x32_bf16(ha, wres[nt][kt], acc[nt], 0, 0, 0);
    }
    // + x W_in^T
#pragma unroll
    for (int kt = 0; kt < 2; ++kt) {
#pragma unroll
      for (int nt = 0; nt < 4; ++nt)
        acc[nt] = __builtin_amdgcn_mfma_f32_16x16x32_bf16(xa[kt], win[nt][kt], acc[nt], 0, 0, 0);
    }

    // leaky update (fp32 state) + store bf16 h_{t+1} to other buffer
#pragma unroll
    for (int nt = 0; nt < 4; ++nt) {
#pragma unroll
      for (int i = 0; i < 4; ++i) {
        float hn = 0.7f * hreg[nt][i] + 0.3f * fast_tanh(acc[nt][i]);
        hreg[nt][i] = hn;
        hs[p ^ 1][lg * 4 + i][w * 64 + nt * 16 + lr] = f2bs(hn);
      }
    }
    __syncthreads();
  }

  // write final state to cat[:, 0:256]
#pragma unroll
  for (int nt = 0; nt < 4; ++nt)
#pragma unroll
    for (int i = 0; i < 4; ++i)
      cat[(gn0 + lg * 4 + i) * (long)CATD + w * 64 + nt * 16 + lr] = hreg[nt][i];
}

// ---------------- SpMV hop (bitmask, dedup'd) ----------------
// out[n][r] = dinv[n] * sum_{j in adj(n)} dinv[j] * in[j][r]
__global__ __launch_bounds__(256) void spmv_kernel(
    const unsigned int* __restrict__ mask, const float* __restrict__ dinv,
    float* __restrict__ catbuf, int k)
{
  __shared__ unsigned int mrow[MASKW];
  const int n = blockIdx.x;
  const int tid = threadIdx.x;
  mrow[tid] = mask[(size_t)n * MASKW + tid];
  __syncthreads();
  const float* in = catbuf + (size_t)(k - 1) * RR;  // slice k-1, row stride CATD
  float acc = 0.0f;
  for (int w = 0; w < MASKW; ++w) {
    unsigned int m = mrow[w];
    while (m) {
      int b = __ffs(m) - 1;
      m &= m - 1;
      int j = __builtin_amdgcn_readfirstlane(w * 32 + b);  // uniform -> s_load dinv
      acc += dinv[j] * in[(size_t)j * CATD + tid];
    }
  }
  catbuf[(size_t)n * CATD + (size_t)k * RR + tid] = acc * dinv[n];
}

// ---------------- fused readout: GEMM1+GELU+GEMM2+LayerNorm ----------------
__global__ __launch_bounds__(256) void readout_kernel(
    const float* __restrict__ cat, const float* __restrict__ W1T,
    const float* __restrict__ b1, const float* __restrict__ W2T,
    const float* __restrict__ b2, const float* __restrict__ gamma,
    const float* __restrict__ beta, float* __restrict__ out)
{
  __shared__ float catl[8][CATD];
  __shared__ float z1[8][HID];
  __shared__ float z2[8][DOUT];
  const int tid = threadIdx.x;
  const long gn0 = (long)blockIdx.x * 8;

  const float4* src = (const float4*)(cat + gn0 * CATD);
  float4* dstl = (float4*)catl;
  for (int i = tid; i < 8 * CATD / 4; i += 256) dstl[i] = src[i];
  __syncthreads();

  {
    const int i = tid & 127;
    const int nh = tid >> 7;       // 2 halves x 4 nodes
    float a0 = b1[i], a1 = a0, a2 = a0, a3 = a0;
#pragma unroll 4
    for (int c = 0; c < CATD; ++c) {
      float w = W1T[c * HID + i];
      a0 += w * catl[nh * 4 + 0][c];
      a1 += w * catl[nh * 4 + 1][c];
      a2 += w * catl[nh * 4 + 2][c];
      a3 += w * catl[nh * 4 + 3][c];
    }
    const float is2 = 0.70710678118654752f;
    z1[nh * 4 + 0][i] = 0.5f * a0 * (1.0f + erff(a0 * is2));
    z1[nh * 4 + 1][i] = 0.5f * a1 * (1.0f + erff(a1 * is2));
    z1[nh * 4 + 2][i] = 0.5f * a2 * (1.0f + erff(a2 * is2));
    z1[nh * 4 + 3][i] = 0.5f * a3 * (1.0f + erff(a3 * is2));
  }
  __syncthreads();
  {
    const int o = tid & 63;
    const int q = tid >> 6;        // 4 quarters x 2 nodes
    float a0 = b2[o], a1 = b2[o];
#pragma unroll 4
    for (int i2 = 0; i2 < HID; ++i2) {
      float w = W2T[i2 * DOUT + o];
      a0 += w * z1[q * 2 + 0][i2];
      a1 += w * z1[q * 2 + 1][i2];
    }
    z2[q * 2 + 0][o] = a0;
    z2[q * 2 + 1][o] = a1;
  }
  __syncthreads();
  {
    const int o = tid & 63;
    const int q = tid >> 6;
#pragma unroll
    for (int m = 0; m < 2; ++m) {
      const int n = q * 2 + m;
      float s = 0.0f, s2 = 0.0f;
#pragma unroll 8
      for (int k2 = 0; k2 < DOUT; ++k2) { float v = z2[n][k2]; s += v; s2 += v * v; }
      float mu  = s * (1.0f / 64.0f);
      float var = s2 * (1.0f / 64.0f) - mu * mu;
      float v = (z2[n][o] - mu) * rsqrtf(var + 1e-5f);
      out[(gn0 + n) * DOUT + o] = v * gamma[o] + beta[o];
    }
  }
}

// ---------------- launch ----------------

extern "C" void kernel_launch(void* const* d_in, const int* in_sizes, int n_in,
                              void* d_out, int out_size, void* d_ws, size_t ws_size,
                              hipStream_t stream) {
  const float* x     = (const float*)d_in[0];
  const int*   eidx  = (const int*)d_in[1];
  const float* W_in  = (const float*)d_in[2];
  const float* W_res = (const float*)d_in[3];
  const float* W1    = (const float*)d_in[4];
  const float* b1    = (const float*)d_in[5];
  const float* W2    = (const float*)d_in[6];
  const float* b2    = (const float*)d_in[7];
  const float* gamma = (const float*)d_in[8];
  const float* beta  = (const float*)d_in[9];
  float* out = (float*)d_out;

  char* ws = (char*)d_ws;
  size_t off = 0;
  unsigned int* mask = (unsigned int*)(ws + off); off += (size_t)NN * MASKW * 4;      // 8 MB
  float* cat   = (float*)(ws + off); off += (size_t)NN * CATD * 4;                    // 32 MB
  float* dinv  = (float*)(ws + off); off += (size_t)NN * 4;
  float* WinT  = (float*)(ws + off); off += (size_t)DIN * RR * 4;                     // unused now
  float* WresT = (float*)(ws + off); off += (size_t)RR * RR * 4;                      // unused now
  float* W1T   = (float*)(ws + off); off += (size_t)CATD * HID * 4;
  float* W2T   = (float*)(ws + off); off += (size_t)HID * DOUT * 4;
  (void)WinT; (void)WresT;

  zero_mask_kernel<<<2048, 256, 0, stream>>>((uint4*)mask, NN * MASKW / 4);
  transpose_kernel<<<512, 256, 0, stream>>>(W1, W1T, HID, CATD);
  transpose_kernel<<<32, 256, 0, stream>>>(W2, W2T, DOUT, HID);
  edge_kernel<<<(NE + 255) / 256, 256, 0, stream>>>(eidx, mask);
  degree_kernel<<<NN, 64, 0, stream>>>(mask, dinv);

  esn_mfma_kernel<<<NN / 16, 256, 0, stream>>>(x, W_in, W_res, cat);

  for (int k = 1; k <= 3; ++k)
    spmv_kernel<<<NN, 256, 0, stream>>>(mask, dinv, cat, k);

  readout_kernel<<<NN / 8, 256, 0, stream>>>(cat, W1T, b1, W2T, b2, gamma, beta, out);
}

// Round 3
// 236.470 us; speedup vs baseline: 7.5024x; 2.6310x over previous
//
#include <hip/hip_runtime.h>
#include <hip/hip_bf16.h>
#include <hip/hip_fp16.h>
#include <math.h>

#define NN    8192
#define TT    64
#define DIN   64
#define RR    256
#define DOUT  64
#define HID   128
#define CATD  1024
#define NE    131072
#define MASKW 256              // 8192 bits / 32
#define MAXD  256              // neighbor list capacity (avg deg ~32)
#define HROW  328              // 320 + 8 bf16 pad (164 dw = 4 mod 32 banks)

typedef __attribute__((ext_vector_type(8))) short    s16x8;   // 8 bf16 bits
typedef __attribute__((ext_vector_type(8))) _Float16 f16x8;   // 8 fp16
typedef __attribute__((ext_vector_type(4))) float    f32x4;

static __device__ __forceinline__ unsigned short f2bs(float f) {
  union { __hip_bfloat16 b; unsigned short u; } cv;
  cv.b = __float2bfloat16(f);
  return cv.u;
}
static __device__ __forceinline__ unsigned int pack2bf(float a, float b) {
  return (unsigned int)f2bs(a) | ((unsigned int)f2bs(b) << 16);
}
static __device__ __forceinline__ unsigned int pack2h(float a, float b) {
  return (unsigned int)__half_as_ushort(__float2half(a))
       | ((unsigned int)__half_as_ushort(__float2half(b)) << 16);
}
static __device__ __forceinline__ float fast_tanh(float v) {
  // tanh(x) = 1 - 2/(exp2(x*2*log2e)+1); exact saturation at +-inf
  float e = __builtin_amdgcn_exp2f(v * 2.8853900817779268f);
  return 1.0f - 2.0f * __builtin_amdgcn_rcpf(e + 1.0f);
}

// ---------------- setup kernels ----------------

__global__ __launch_bounds__(256) void zero_mask_kernel(uint4* mask4, int n4) {
  int i = blockIdx.x * 256 + threadIdx.x;
  if (i < n4) mask4[i] = make_uint4(0u, 0u, 0u, 0u);
}

__global__ __launch_bounds__(256) void edge_kernel(const int* __restrict__ eidx,
                                                   unsigned int* __restrict__ mask) {
  int e = blockIdx.x * 256 + threadIdx.x;
  if (e < NE) {
    int u = eidx[e];
    int v = eidx[NE + e];
    atomicOr(&mask[(size_t)u * MASKW + (v >> 5)], 1u << (v & 31));
    atomicOr(&mask[(size_t)v * MASKW + (u >> 5)], 1u << (u & 31));
  }
}

__global__ __launch_bounds__(64) void degree_kernel(const unsigned int* __restrict__ mask,
                                                    float* __restrict__ dinv) {
  int n = blockIdx.x;
  int lane = threadIdx.x;
  uint4 mw = *(const uint4*)(mask + (size_t)n * MASKW + lane * 4);
  int c = __popc(mw.x) + __popc(mw.y) + __popc(mw.z) + __popc(mw.w);
#pragma unroll
  for (int off = 32; off > 0; off >>= 1) c += __shfl_down(c, off, 64);
  if (lane == 0) {
    dinv[n] = (c > 0) ? fminf(1.0f / sqrtf((float)c), 1e6f) : 0.0f;
  }
}

// deterministic neighbor list via prefix scan over mask words
__global__ __launch_bounds__(256) void nbrlist_kernel(const unsigned int* __restrict__ mask,
                                                      unsigned short* __restrict__ nbrlist,
                                                      int* __restrict__ nbrcnt) {
  __shared__ int wsum[4];
  const int n = blockIdx.x;
  const int tid = threadIdx.x;
  const int lane = tid & 63;
  const int w = tid >> 6;
  unsigned int m = mask[(size_t)n * MASKW + tid];
  const int c = __popc(m);
  int inc = c;
#pragma unroll
  for (int d = 1; d < 64; d <<= 1) {
    int v = __shfl_up(inc, d, 64);
    if (lane >= d) inc += v;
  }
  if (lane == 63) wsum[w] = inc;
  __syncthreads();
  int base = 0;
  for (int i = 0; i < w; ++i) base += wsum[i];
  int off = base + inc - c;     // exclusive prefix
  while (m) {
    int b = __ffs(m) - 1;
    m &= m - 1;
    if (off < MAXD) nbrlist[(size_t)n * MAXD + off] = (unsigned short)(tid * 32 + b);
    ++off;
  }
  if (tid == 255) {
    int tot = base + inc;
    nbrcnt[n] = tot < MAXD ? tot : MAXD;
  }
}

__global__ __launch_bounds__(256) void cvt_bf16_kernel(const float* __restrict__ s,
                                                       unsigned short* __restrict__ d, int n) {
  int i = blockIdx.x * 256 + threadIdx.x;
  if (i < n) d[i] = f2bs(s[i]);
}
__global__ __launch_bounds__(256) void cvt_f16_kernel(const float* __restrict__ s,
                                                      unsigned short* __restrict__ d, int n) {
  int i = blockIdx.x * 256 + threadIdx.x;
  if (i < n) d[i] = __half_as_ushort(__float2half(s[i]));
}

// ---------------- ESN via bf16 MFMA, augmented K=320 ----------------
// Block: 512 threads = 8 waves, 16 nodes. Wave w owns output r in [w*32, w*32+32).
// Flipped operands: A = W_aug rows (stationary regs), B = [h ; x_t] from LDS.
// D[r][n]: lane holds node lr (col), rows lg*4+i per rtile -> ds_write_b64.
__global__ __launch_bounds__(512, 4) void esn_mfma_kernel(
    const float* __restrict__ x,               // [N][T][DIN] fp32
    const unsigned short* __restrict__ winh,   // [R][DIN] bf16
    const unsigned short* __restrict__ wresh,  // [R][R]   bf16
    unsigned short* __restrict__ cat)          // [N][CATD] fp16, writes cols 0..255
{
  __shared__ unsigned short hs[2][16][HROW];   // [buf][node][k: 0..255 h, 256..319 x]
  const int tid  = threadIdx.x;
  const int lane = tid & 63;
  const int w    = tid >> 6;     // wave 0..7
  const int lr   = lane & 15;
  const int lg   = lane >> 4;
  const int sn   = tid >> 5;     // staging: node 0..15
  const int sd   = tid & 31;     // staging: dword-pair 0..31 (d = sd*2)
  const long gn0 = (long)blockIdx.x * 16;

  // stationary A-fragments: W_aug = [W_res | W_in], 2 rtiles x 10 ktiles
  s16x8 waug[2][10];
#pragma unroll
  for (int rt = 0; rt < 2; ++rt) {
    const int r = w * 32 + rt * 16 + lr;
#pragma unroll
    for (int kt = 0; kt < 8; ++kt)
      waug[rt][kt] = *(const s16x8*)(wresh + r * RR + kt * 32 + lg * 8);
#pragma unroll
    for (int kt = 8; kt < 10; ++kt)
      waug[rt][kt] = *(const s16x8*)(winh + r * DIN + (kt - 8) * 32 + lg * 8);
  }

  // zero buffer 0
  for (int i = tid; i < 16 * HROW / 2; i += 512) ((unsigned int*)hs[0])[i] = 0u;

  // chunk-0 x prefetch (coalesced float2 per (node, d-pair))
  const float* xbase = x + (gn0 + sn) * (long)(TT * DIN) + sd * 2;
  float2 cur[4], nxt[4];
#pragma unroll
  for (int ts = 0; ts < 4; ++ts) cur[ts] = *(const float2*)(xbase + ts * DIN);

  __syncthreads();
  // x_0 into buffer 0
  *(unsigned int*)(&hs[0][sn][RR + sd * 2]) = pack2bf(cur[0].x, cur[0].y);

  f32x4 hreg[2];
  hreg[0] = (f32x4){0.f, 0.f, 0.f, 0.f};
  hreg[1] = (f32x4){0.f, 0.f, 0.f, 0.f};
  __syncthreads();

  for (int tc = 0; tc < TT / 4; ++tc) {
    if (tc < TT / 4 - 1) {
      const float* p = xbase + (tc + 1) * 4 * DIN;
#pragma unroll
      for (int ts = 0; ts < 4; ++ts) nxt[ts] = *(const float2*)(p + ts * DIN);
    }
#pragma unroll
    for (int ts = 0; ts < 4; ++ts) {
      const int t  = tc * 4 + ts;
      const int pb = t & 1;
      f32x4 acc0 = (f32x4){0.f, 0.f, 0.f, 0.f};
      f32x4 acc1 = (f32x4){0.f, 0.f, 0.f, 0.f};
#pragma unroll
      for (int kt = 0; kt < 10; ++kt) {
        const s16x8 hb = *(const s16x8*)(&hs[pb][lr][kt * 32 + lg * 8]);
        acc0 = __builtin_amdgcn_mfma_f32_16x16x32_bf16(waug[0][kt], hb, acc0, 0, 0, 0);
        acc1 = __builtin_amdgcn_mfma_f32_16x16x32_bf16(waug[1][kt], hb, acc1, 0, 0, 0);
      }
      // x_{t+1} into the other buffer (read next step)
      if (t + 1 < TT) {
        const float2 xv = (ts < 3) ? cur[ts + 1] : nxt[0];
        *(unsigned int*)(&hs[pb ^ 1][sn][RR + sd * 2]) = pack2bf(xv.x, xv.y);
      }
      // leaky update (fp32 state), h_{t+1} bf16 -> other buffer
#pragma unroll
      for (int rt = 0; rt < 2; ++rt) {
        const f32x4 a = rt ? acc1 : acc0;
        f32x4 hn;
#pragma unroll
        for (int i = 0; i < 4; ++i)
          hn[i] = 0.7f * hreg[rt][i] + 0.3f * fast_tanh(a[i]);
        hreg[rt] = hn;
        *(uint2*)(&hs[pb ^ 1][lr][w * 32 + rt * 16 + lg * 4]) =
            make_uint2(pack2bf(hn[0], hn[1]), pack2bf(hn[2], hn[3]));
      }
      __syncthreads();
    }
#pragma unroll
    for (int ts = 0; ts < 4; ++ts) cur[ts] = nxt[ts];
  }

  // final state -> cat[:, 0:256] fp16
#pragma unroll
  for (int rt = 0; rt < 2; ++rt) {
    *(uint2*)(cat + (gn0 + lr) * CATD + w * 32 + rt * 16 + lg * 4) =
        make_uint2(pack2h(hreg[rt][0], hreg[rt][1]), pack2h(hreg[rt][2], hreg[rt][3]));
  }
}

// ---------------- SpMV hop (neighbor list, fp16 gathers) ----------------
__global__ __launch_bounds__(256) void spmv_kernel(
    const unsigned short* __restrict__ nbrlist, const int* __restrict__ nbrcnt,
    const float* __restrict__ dinv, unsigned short* __restrict__ cat, int hop)
{
  const int n = blockIdx.x;
  const int tid = threadIdx.x;
  const int cnt = nbrcnt[n];
  const unsigned short* lp = nbrlist + (size_t)n * MAXD;
  const __half* in = (const __half*)cat + (size_t)(hop - 1) * RR;
  float acc = 0.0f;
  int i = 0;
  for (; i + 4 <= cnt; i += 4) {
    const int j0 = __builtin_amdgcn_readfirstlane((int)lp[i + 0]);
    const int j1 = __builtin_amdgcn_readfirstlane((int)lp[i + 1]);
    const int j2 = __builtin_amdgcn_readfirstlane((int)lp[i + 2]);
    const int j3 = __builtin_amdgcn_readfirstlane((int)lp[i + 3]);
    const float v0 = __half2float(in[(size_t)j0 * CATD + tid]);
    const float v1 = __half2float(in[(size_t)j1 * CATD + tid]);
    const float v2 = __half2float(in[(size_t)j2 * CATD + tid]);
    const float v3 = __half2float(in[(size_t)j3 * CATD + tid]);
    acc += dinv[j0] * v0;
    acc += dinv[j1] * v1;
    acc += dinv[j2] * v2;
    acc += dinv[j3] * v3;
  }
  for (; i < cnt; ++i) {
    const int j = __builtin_amdgcn_readfirstlane((int)lp[i]);
    acc += dinv[j] * __half2float(in[(size_t)j * CATD + tid]);
  }
  cat[(size_t)n * CATD + (size_t)hop * RR + tid] =
      __half_as_ushort(__float2half(acc * dinv[n]));
}

// ---------------- fused readout: MFMA GEMM1 + GELU + GEMM2 + LayerNorm ----------------
// Block: 256 threads = 4 waves, 16 nodes. GEMM1: wave w -> hid tiles 2w, 2w+1.
__global__ __launch_bounds__(256) void readout_kernel(
    const unsigned short* __restrict__ cat,  // [N][1024] fp16
    const unsigned short* __restrict__ W1h,  // [128][1024] fp16
    const float* __restrict__ b1,
    const unsigned short* __restrict__ W2h,  // [64][128] fp16
    const float* __restrict__ b2, const float* __restrict__ gamma,
    const float* __restrict__ beta, float* __restrict__ out)
{
  __shared__ unsigned short z1[16][136];   // fp16, pad 136 (272B = 68 dw = 4 mod 32)
  __shared__ float z2[16][68];
  const int tid  = threadIdx.x;
  const int lane = tid & 63;
  const int w    = tid >> 6;
  const int lr   = lane & 15;
  const int lg   = lane >> 4;
  const long gn0 = (long)blockIdx.x * 16;

  // GEMM1: D1[node][hid] = cat(16x1024) @ W1^T
  f32x4 a0 = (f32x4){0.f, 0.f, 0.f, 0.f};
  f32x4 a1 = (f32x4){0.f, 0.f, 0.f, 0.f};
  const unsigned short* arow  = cat + (gn0 + lr) * CATD;       // A row: node lr
  const unsigned short* b0row = W1h + (w * 32 + lr) * CATD;    // B col: hid w*32+lr
  const unsigned short* b1row = W1h + (w * 32 + 16 + lr) * CATD;
#pragma unroll 8
  for (int kt = 0; kt < 32; ++kt) {
    const f16x8 af  = *(const f16x8*)(arow  + kt * 32 + lg * 8);
    const f16x8 bf0 = *(const f16x8*)(b0row + kt * 32 + lg * 8);
    const f16x8 bf1 = *(const f16x8*)(b1row + kt * 32 + lg * 8);
    a0 = __builtin_amdgcn_mfma_f32_16x16x32_f16(af, bf0, a0, 0, 0, 0);
    a1 = __builtin_amdgcn_mfma_f32_16x16x32_f16(af, bf1, a1, 0, 0, 0);
  }
  // bias + GELU(erf) -> z1 fp16
  const float is2 = 0.70710678118654752f;
#pragma unroll
  for (int nt = 0; nt < 2; ++nt) {
    const int hid = w * 32 + nt * 16 + lr;
    const float bb = b1[hid];
    const f32x4 a = nt ? a1 : a0;
#pragma unroll
    for (int i = 0; i < 4; ++i) {
      const float v = a[i] + bb;
      const float g = 0.5f * v * (1.0f + erff(v * is2));
      z1[lg * 4 + i][hid] = __half_as_ushort(__float2half(g));
    }
  }
  __syncthreads();

  // GEMM2: D2[node][o] = z1(16x128) @ W2^T ; wave w -> out tile w (o = w*16+lr)
  f32x4 c2 = (f32x4){0.f, 0.f, 0.f, 0.f};
  const unsigned short* w2row = W2h + (w * 16 + lr) * HID;
#pragma unroll
  for (int kt = 0; kt < 4; ++kt) {
    const f16x8 af = *(const f16x8*)(&z1[lr][kt * 32 + lg * 8]);
    const f16x8 bf = *(const f16x8*)(w2row + kt * 32 + lg * 8);
    c2 = __builtin_amdgcn_mfma_f32_16x16x32_f16(af, bf, c2, 0, 0, 0);
  }
  {
    const float bb = b2[w * 16 + lr];
#pragma unroll
    for (int i = 0; i < 4; ++i) z2[lg * 4 + i][w * 16 + lr] = c2[i] + bb;
  }
  __syncthreads();

  // LayerNorm over 64 out-dims; 16 threads per node (lanes grouped)
  {
    const int n = tid >> 4;
    const int c = tid & 15;
    const float v0 = z2[n][c], v1 = z2[n][c + 16], v2 = z2[n][c + 32], v3 = z2[n][c + 48];
    float s  = v0 + v1 + v2 + v3;
    float s2 = v0 * v0 + v1 * v1 + v2 * v2 + v3 * v3;
#pragma unroll
    for (int m = 1; m < 16; m <<= 1) {
      s  += __shfl_xor(s,  m, 64);
      s2 += __shfl_xor(s2, m, 64);
    }
    const float mu  = s * (1.0f / 64.0f);
    const float var = s2 * (1.0f / 64.0f) - mu * mu;
    const float inv = rsqrtf(var + 1e-5f);
    float* orow = out + (gn0 + n) * DOUT;
    orow[c]      = (v0 - mu) * inv * gamma[c]      + beta[c];
    orow[c + 16] = (v1 - mu) * inv * gamma[c + 16] + beta[c + 16];
    orow[c + 32] = (v2 - mu) * inv * gamma[c + 32] + beta[c + 32];
    orow[c + 48] = (v3 - mu) * inv * gamma[c + 48] + beta[c + 48];
  }
}

// ---------------- launch ----------------

extern "C" void kernel_launch(void* const* d_in, const int* in_sizes, int n_in,
                              void* d_out, int out_size, void* d_ws, size_t ws_size,
                              hipStream_t stream) {
  const float* x     = (const float*)d_in[0];
  const int*   eidx  = (const int*)d_in[1];
  const float* W_in  = (const float*)d_in[2];
  const float* W_res = (const float*)d_in[3];
  const float* W1    = (const float*)d_in[4];
  const float* b1    = (const float*)d_in[5];
  const float* W2    = (const float*)d_in[6];
  const float* b2    = (const float*)d_in[7];
  const float* gamma = (const float*)d_in[8];
  const float* beta  = (const float*)d_in[9];
  float* out = (float*)d_out;

  char* ws = (char*)d_ws;
  size_t off = 0;
  auto alloc = [&](size_t bytes) {
    void* p = ws + off;
    off += (bytes + 255) & ~(size_t)255;
    return p;
  };
  unsigned int*   mask    = (unsigned int*)  alloc((size_t)NN * MASKW * 4);  // 8 MB
  unsigned short* cat     = (unsigned short*)alloc((size_t)NN * CATD * 2);   // 16 MB
  unsigned short* nbrlist = (unsigned short*)alloc((size_t)NN * MAXD * 2);   // 4 MB
  int*            nbrcnt  = (int*)           alloc((size_t)NN * 4);
  float*          dinv    = (float*)         alloc((size_t)NN * 4);
  unsigned short* wresh   = (unsigned short*)alloc((size_t)RR * RR * 2);
  unsigned short* winh    = (unsigned short*)alloc((size_t)RR * DIN * 2);
  unsigned short* W1h     = (unsigned short*)alloc((size_t)HID * CATD * 2);
  unsigned short* W2h     = (unsigned short*)alloc((size_t)DOUT * HID * 2);

  zero_mask_kernel<<<2048, 256, 0, stream>>>((uint4*)mask, NN * MASKW / 4);
  edge_kernel<<<NE / 256, 256, 0, stream>>>(eidx, mask);
  degree_kernel<<<NN, 64, 0, stream>>>(mask, dinv);
  nbrlist_kernel<<<NN, 256, 0, stream>>>(mask, nbrlist, nbrcnt);
  cvt_bf16_kernel<<<RR * RR / 256, 256, 0, stream>>>(W_res, wresh, RR * RR);
  cvt_bf16_kernel<<<RR * DIN / 256, 256, 0, stream>>>(W_in, winh, RR * DIN);
  cvt_f16_kernel<<<HID * CATD / 256, 256, 0, stream>>>(W1, W1h, HID * CATD);
  cvt_f16_kernel<<<DOUT * HID / 256, 256, 0, stream>>>(W2, W2h, DOUT * HID);

  esn_mfma_kernel<<<NN / 16, 512, 0, stream>>>(x, winh, wresh, cat);

  for (int k = 1; k <= 3; ++k)
    spmv_kernel<<<NN, 256, 0, stream>>>(nbrlist, nbrcnt, dinv, cat, k);

  readout_kernel<<<NN / 16, 256, 0, stream>>>(cat, W1h, b1, W2h, b2, gamma, beta, out);
}